// Round 1
// baseline (1179.470 us; speedup 1.0000x reference)
//
#include <hip/hip_runtime.h>

typedef float f32x4 __attribute__((ext_vector_type(4)));
typedef __bf16 bf16x8 __attribute__((ext_vector_type(8)));
typedef short s16x8 __attribute__((ext_vector_type(8)));
typedef unsigned short u16;

#define DEV static __device__ __forceinline__

DEV u16 f2bf_rn(float f) {
    unsigned u = __float_as_uint(f);
    return (u16)((u + 0x7fffu + ((u >> 16) & 1u)) >> 16);
}
DEV float bf2f(u16 h) { return __uint_as_float(((unsigned)h) << 16); }

typedef __attribute__((address_space(3))) unsigned int lds_u32;
typedef __attribute__((address_space(1))) const unsigned int glb_u32;

DEV void gload16(const void* g, void* l) {
    __builtin_amdgcn_global_load_lds((glb_u32*)g, (lds_u32*)l, 16, 0, 0);
}

// ---------------- transpose / convert ----------------
// src [R][C] f32 -> out [C][R]; SPLIT: hi/lo bf16 (+ optional f32 copy), else bf16
template <bool SPLIT>
__global__ __launch_bounds__(256) void tr_kernel(const float* __restrict__ src, int R, int C,
                                                 u16* __restrict__ hiT, u16* __restrict__ loT,
                                                 float* __restrict__ f32T) {
    __shared__ float t[32][33];
    int tx = threadIdx.x, ty = threadIdx.y;
    int c0 = blockIdx.x * 32, r0 = blockIdx.y * 32;
#pragma unroll
    for (int i = 0; i < 4; i++) {
        int r = r0 + ty + i * 8;
        t[ty + i * 8][tx] = src[(size_t)r * C + c0 + tx];
    }
    __syncthreads();
#pragma unroll
    for (int i = 0; i < 4; i++) {
        int c = c0 + ty + i * 8;
        float v = t[tx][ty + i * 8];
        size_t o = (size_t)c * R + r0 + tx;
        if (SPLIT) {
            u16 hi = f2bf_rn(v);
            float rem = v - bf2f(hi);
            hiT[o] = hi;
            loT[o] = f2bf_rn(rem);
            if (f32T) f32T[o] = v;
        } else {
            hiT[o] = f2bf_rn(v);
        }
    }
}

// ---------------- GEMM1: h = relu(X f32 @ We1 + be1), split-bf16 3-pass ----------------
// BM=64 BN=128 BK=64, 256 threads (4 waves 2x2)
__global__ __launch_bounds__(256) void gemm1_split(const float* __restrict__ A,       // [4096][12288]
                                                   const u16* __restrict__ BThi,      // [1024][12288]
                                                   const u16* __restrict__ BTlo,
                                                   const float* __restrict__ bias,
                                                   float* __restrict__ H) {           // [4096][1024]
    constexpr int K = 12288, N = 1024;
    __shared__ __align__(16) u16 Ahi[64][64];
    __shared__ __align__(16) u16 Alo[64][64];
    __shared__ __align__(16) u16 Bhi[128][64];
    __shared__ __align__(16) u16 Blo[128][64];
    int tid = threadIdx.x;
    int lane = tid & 63, wid = tid >> 6;
    int wr = wid >> 1, wc = wid & 1;
    int m0 = blockIdx.x * 64, n0 = blockIdx.y * 128;

    f32x4 acc[2][4] = {};
    for (int kt = 0; kt < K / 64; ++kt) {
        int k0 = kt * 64;
        // B tiles: async global->LDS
#pragma unroll
        for (int i = 0; i < 4; i++) {
            int s = i * 256 + tid;
            int r = s >> 3, c8 = (s & 7) * 8;
            gload16(BThi + (size_t)(n0 + r) * K + k0 + c8, &Bhi[r][c8]);
            gload16(BTlo + (size_t)(n0 + r) * K + k0 + c8, &Blo[r][c8]);
        }
        // A tile: reg-staged fp32 -> hi/lo (truncation split)
#pragma unroll
        for (int i = 0; i < 4; i++) {
            int s = i * 256 + tid;
            int r = s >> 4, c4 = (s & 15) * 4;
            f32x4 v = *(const f32x4*)(A + (size_t)(m0 + r) * K + k0 + c4);
            unsigned hi[4], lo[4];
#pragma unroll
            for (int j = 0; j < 4; j++) {
                unsigned u = __float_as_uint(v[j]);
                unsigned hf = u & 0xffff0000u;
                hi[j] = u >> 16;
                float rf = v[j] - __uint_as_float(hf);
                lo[j] = __float_as_uint(rf) >> 16;
            }
            unsigned h01 = hi[0] | (hi[1] << 16), h23 = hi[2] | (hi[3] << 16);
            unsigned l01 = lo[0] | (lo[1] << 16), l23 = lo[2] | (lo[3] << 16);
            *(uint2*)&Ahi[r][c4] = make_uint2(h01, h23);
            *(uint2*)&Alo[r][c4] = make_uint2(l01, l23);
        }
        __syncthreads();
#pragma unroll
        for (int kk = 0; kk < 2; kk++) {
            int kb = kk * 32 + (lane >> 4) * 8;
            bf16x8 ah[2], al[2], bh[4], bl[4];
#pragma unroll
            for (int mi = 0; mi < 2; mi++) {
                int r = wr * 32 + mi * 16 + (lane & 15);
                ah[mi] = __builtin_bit_cast(bf16x8, *(const s16x8*)&Ahi[r][kb]);
                al[mi] = __builtin_bit_cast(bf16x8, *(const s16x8*)&Alo[r][kb]);
            }
#pragma unroll
            for (int ni = 0; ni < 4; ni++) {
                int r = wc * 64 + ni * 16 + (lane & 15);
                bh[ni] = __builtin_bit_cast(bf16x8, *(const s16x8*)&Bhi[r][kb]);
                bl[ni] = __builtin_bit_cast(bf16x8, *(const s16x8*)&Blo[r][kb]);
            }
#pragma unroll
            for (int mi = 0; mi < 2; mi++)
#pragma unroll
                for (int ni = 0; ni < 4; ni++) {
                    acc[mi][ni] = __builtin_amdgcn_mfma_f32_16x16x32_bf16(ah[mi], bh[ni], acc[mi][ni], 0, 0, 0);
                    acc[mi][ni] = __builtin_amdgcn_mfma_f32_16x16x32_bf16(ah[mi], bl[ni], acc[mi][ni], 0, 0, 0);
                    acc[mi][ni] = __builtin_amdgcn_mfma_f32_16x16x32_bf16(al[mi], bh[ni], acc[mi][ni], 0, 0, 0);
                }
        }
        __syncthreads();
    }
#pragma unroll
    for (int ni = 0; ni < 4; ni++) {
        int col = n0 + wc * 64 + ni * 16 + (lane & 15);
        float bv = bias[col];
#pragma unroll
        for (int mi = 0; mi < 2; mi++) {
            int rb = m0 + wr * 32 + mi * 16 + (lane >> 4) * 4;
#pragma unroll
            for (int j = 0; j < 4; j++) {
                float x = acc[mi][ni][j] + bv;
                H[(size_t)(rb + j) * N + col] = x > 0.f ? x : 0.f;
            }
        }
    }
}

// ---------------- generic bf16 BT GEMM, EPI: 1=relu->bf16, 2=sigmoid->f32 ----------------
template <int BM, int BN, int EPI>
__global__ __launch_bounds__(256) void gemm_bt(const u16* __restrict__ A,   // [M][K] bf16
                                               const u16* __restrict__ BT,  // [N][K] bf16
                                               const float* __restrict__ bias,
                                               void* __restrict__ Out, int M, int N, int K) {
    constexpr int WM = BM / 2, WN = BN / 2, MI = WM / 16, NI = WN / 16;
    __shared__ __align__(16) u16 As[BM][64];
    __shared__ __align__(16) u16 Bs[BN][64];
    int tid = threadIdx.x, lane = tid & 63, wid = tid >> 6;
    int wr = wid >> 1, wc = wid & 1;
    int m0 = blockIdx.x * BM, n0 = blockIdx.y * BN;
    f32x4 acc[MI][NI] = {};
    for (int kt = 0; kt < K / 64; ++kt) {
        int k0 = kt * 64;
#pragma unroll
        for (int i = 0; i < BM / 32; i++) {
            int s = i * 256 + tid;
            int r = s >> 3, c8 = (s & 7) * 8;
            gload16(A + (size_t)(m0 + r) * K + k0 + c8, &As[r][c8]);
        }
#pragma unroll
        for (int i = 0; i < BN / 32; i++) {
            int s = i * 256 + tid;
            int r = s >> 3, c8 = (s & 7) * 8;
            gload16(BT + (size_t)(n0 + r) * K + k0 + c8, &Bs[r][c8]);
        }
        __syncthreads();
#pragma unroll
        for (int kk = 0; kk < 2; kk++) {
            int kb = kk * 32 + (lane >> 4) * 8;
            bf16x8 af[MI], bfr[NI];
#pragma unroll
            for (int mi = 0; mi < MI; mi++)
                af[mi] = __builtin_bit_cast(bf16x8, *(const s16x8*)&As[wr * WM + mi * 16 + (lane & 15)][kb]);
#pragma unroll
            for (int ni = 0; ni < NI; ni++)
                bfr[ni] = __builtin_bit_cast(bf16x8, *(const s16x8*)&Bs[wc * WN + ni * 16 + (lane & 15)][kb]);
#pragma unroll
            for (int mi = 0; mi < MI; mi++)
#pragma unroll
                for (int ni = 0; ni < NI; ni++)
                    acc[mi][ni] = __builtin_amdgcn_mfma_f32_16x16x32_bf16(af[mi], bfr[ni], acc[mi][ni], 0, 0, 0);
        }
        __syncthreads();
    }
#pragma unroll
    for (int ni = 0; ni < NI; ni++) {
        int col = n0 + wc * WN + ni * 16 + (lane & 15);
        float bv = bias[col];
#pragma unroll
        for (int mi = 0; mi < MI; mi++) {
            int rb = m0 + wr * WM + mi * 16 + (lane >> 4) * 4;
#pragma unroll
            for (int j = 0; j < 4; j++) {
                float x = acc[mi][ni][j] + bv;
                if (EPI == 1) {
                    ((u16*)Out)[(size_t)(rb + j) * N + col] = f2bf_rn(x > 0.f ? x : 0.f);
                } else {
                    float s = 1.f / (1.f + __expf(-x));
                    ((float*)Out)[(size_t)(rb + j) * N + col] = s;
                }
            }
        }
    }
}

// ---------------- top-64 of 1024 per row: threshold via bit binary search ----------------
__global__ __launch_bounds__(256) void topk_kernel(const float* __restrict__ H,
                                                   u16* __restrict__ HM,
                                                   float* __restrict__ rowT,
                                                   unsigned* __restrict__ rowFlag) {
    int row = blockIdx.x * 4 + (threadIdx.x >> 6);
    int lane = threadIdx.x & 63;
    const float* hr = H + (size_t)row * 1024;
    float v[16];
#pragma unroll
    for (int i = 0; i < 4; i++) *(f32x4*)&v[i * 4] = *(const f32x4*)(hr + lane * 16 + i * 4);
    unsigned u[16];
#pragma unroll
    for (int i = 0; i < 16; i++) u[i] = __float_as_uint(v[i]);
    unsigned lo = 0;
    for (int b = 30; b >= 0; --b) {
        unsigned cand = lo | (1u << b);
        int c = 0;
#pragma unroll
        for (int i = 0; i < 16; i++) c += (u[i] >= cand);
#pragma unroll
        for (int off = 32; off; off >>= 1) c += __shfl_xor(c, off);
        if (c >= 64) lo = cand;
    }
    unsigned m2 = 0;
#pragma unroll
    for (int i = 0; i < 16; i++)
        if (u[i] < lo && u[i] > m2) m2 = u[i];
#pragma unroll
    for (int off = 32; off; off >>= 1) {
        unsigned o = __shfl_xor(m2, off);
        if (o > m2) m2 = o;
    }
    u16 o16[16];
#pragma unroll
    for (int i = 0; i < 16; i++) o16[i] = (u[i] >= lo) ? f2bf_rn(v[i]) : (u16)0;
    unsigned p[8];
#pragma unroll
    for (int i = 0; i < 8; i++) p[i] = (unsigned)o16[2 * i] | ((unsigned)o16[2 * i + 1] << 16);
    u16* dst = HM + (size_t)row * 1024 + lane * 16;
    *(uint4*)dst = make_uint4(p[0], p[1], p[2], p[3]);
    *(uint4*)(dst + 8) = make_uint4(p[4], p[5], p[6], p[7]);
    if (lane == 0) {
        rowT[row] = __uint_as_float(lo);
        float t = __uint_as_float(lo), s = __uint_as_float(m2);
        rowFlag[row] = (lo != 0u) && (t - s < 1e-4f);
    }
}

// ---------------- fp64 fix-up of boundary-ambiguous selections ----------------
__global__ __launch_bounds__(64) void fixup_kernel(const float* __restrict__ H,
                                                   const float* __restrict__ X,
                                                   const float* __restrict__ W, long jstride, long kstride,
                                                   const float* __restrict__ be1,
                                                   const float* __restrict__ rowT,
                                                   const unsigned* __restrict__ rowFlag,
                                                   u16* __restrict__ HM) {
    int row = blockIdx.x;
    if (!rowFlag[row]) return;
    int lane = threadIdx.x;
    const float BAND = 1e-4f;
    float Tf = rowT[row];
    const float* hr = H + (size_t)row * 1024;
    float v[16];
#pragma unroll
    for (int i = 0; i < 4; i++) *(f32x4*)&v[i * 4] = *(const f32x4*)(hr + lane * 16 + i * 4);
    __shared__ int bidx[64];
    __shared__ float bval[64];
    __shared__ double dval[64];
    int base = 0, csure = 0;
#pragma unroll
    for (int i = 0; i < 16; i++) {
        bool inb = fabsf(v[i] - Tf) <= BAND;
        csure += (v[i] > Tf + BAND);
        unsigned long long mk = __ballot(inb);
        if (inb) {
            int pos = base + __popcll(mk & ((1ull << lane) - 1ull));
            if (pos < 64) { bidx[pos] = lane * 16 + i; bval[pos] = v[i]; }
        }
        base += (int)__popcll(mk);
    }
#pragma unroll
    for (int off = 32; off; off >>= 1) csure += __shfl_xor(csure, off);
    int nb = base > 64 ? 64 : base;
    __syncthreads();
    if (nb < 2) return;
    int kband = 64 - csure;
    const float* xr = X + (size_t)row * 12288;
    for (int e = 0; e < nb; e++) {
        int j = bidx[e];
        const float* wp = W + (size_t)j * jstride;
        double s = 0.0;
        for (int k = lane; k < 12288; k += 64) s += (double)xr[k] * (double)wp[(size_t)k * kstride];
#pragma unroll
        for (int off = 32; off; off >>= 1) s += __shfl_xor(s, off);
        if (lane == 0) dval[e] = s + (double)be1[j];
    }
    __syncthreads();
    if (lane < nb) {
        double me = dval[lane];
        int j = bidx[lane];
        int rank = 0;
        for (int f = 0; f < nb; f++) {
            double df = dval[f];
            rank += (df > me) || (df == me && bidx[f] < j);
        }
        bool keep = rank < kband;
        HM[(size_t)row * 1024 + j] = keep ? f2bf_rn(bval[lane]) : (u16)0;
    }
}

extern "C" void kernel_launch(void* const* d_in, const int* in_sizes, int n_in,
                              void* d_out, int out_size, void* d_ws, size_t ws_size,
                              hipStream_t stream) {
    const float* X   = (const float*)d_in[0];
    const float* We1 = (const float*)d_in[1];
    const float* be1 = (const float*)d_in[2];
    const float* Wd1 = (const float*)d_in[3];
    const float* bd1 = (const float*)d_in[4];
    const float* Wd2 = (const float*)d_in[5];
    const float* bd2 = (const float*)d_in[6];

    char* ws = (char*)d_ws;
    size_t off = 0;
    auto alloc = [&](size_t bytes) { void* p = ws + off; off += (bytes + 255) & ~(size_t)255; return p; };
    u16* W1hiT = (u16*)alloc(12288ull * 1024 * 2);
    u16* W1loT = (u16*)alloc(12288ull * 1024 * 2);
    u16* Wd1T  = (u16*)alloc(1024ull * 1024 * 2);
    u16* Wd2T  = (u16*)alloc(1024ull * 12288 * 2);
    float* Hbuf = (float*)alloc(4096ull * 1024 * 4);
    u16* HM    = (u16*)alloc(4096ull * 1024 * 2);
    u16* Dbf   = (u16*)alloc(4096ull * 1024 * 2);
    float* rowT = (float*)alloc(4096 * 4);
    unsigned* rowFlag = (unsigned*)alloc(4096 * 4);
    float* We1Tf = nullptr;
    if (off + 12288ull * 1024 * 4 <= ws_size) We1Tf = (float*)alloc(12288ull * 1024 * 4);

    dim3 tb(32, 8);
    // We1 [12288][1024] -> [1024][12288] hi/lo (+f32 if ws allows)
    tr_kernel<true><<<dim3(1024 / 32, 12288 / 32), tb, 0, stream>>>(We1, 12288, 1024, W1hiT, W1loT, We1Tf);
    // Wd1 [1024][1024] -> [1024][1024] bf16
    tr_kernel<false><<<dim3(1024 / 32, 1024 / 32), tb, 0, stream>>>(Wd1, 1024, 1024, Wd1T, nullptr, nullptr);
    // Wd2 [1024][12288] -> [12288][1024] bf16
    tr_kernel<false><<<dim3(12288 / 32, 1024 / 32), tb, 0, stream>>>(Wd2, 1024, 12288, Wd2T, nullptr, nullptr);

    gemm1_split<<<dim3(4096 / 64, 1024 / 128), 256, 0, stream>>>(X, W1hiT, W1loT, be1, Hbuf);
    topk_kernel<<<dim3(4096 / 4), 256, 0, stream>>>(Hbuf, HM, rowT, rowFlag);
    if (We1Tf)
        fixup_kernel<<<4096, 64, 0, stream>>>(Hbuf, X, We1Tf, 12288, 1, be1, rowT, rowFlag, HM);
    else
        fixup_kernel<<<4096, 64, 0, stream>>>(Hbuf, X, We1, 1, 1024, be1, rowT, rowFlag, HM);
    gemm_bt<64, 128, 1><<<dim3(4096 / 64, 1024 / 128), 256, 0, stream>>>(HM, Wd1T, bd1, Dbf, 4096, 1024, 1024);
    gemm_bt<128, 128, 2><<<dim3(4096 / 128, 12288 / 128), 256, 0, stream>>>(Dbf, Wd2T, bd2, d_out, 4096, 12288, 1024);
}

// Round 2
// 819.240 us; speedup vs baseline: 1.4397x; 1.4397x over previous
//
#include <hip/hip_runtime.h>

typedef float f32x4 __attribute__((ext_vector_type(4)));
typedef __bf16 bf16x8 __attribute__((ext_vector_type(8)));
typedef _Float16 f16x8 __attribute__((ext_vector_type(8)));
typedef short s16x8 __attribute__((ext_vector_type(8)));
typedef unsigned short u16;

#define DEV static __device__ __forceinline__

#define SEL_BAND 2.0e-3f   // fp16-GEMM1 error band for exact re-ranking

DEV u16 f2bf_rn(float f) {
    unsigned u = __float_as_uint(f);
    return (u16)((u + 0x7fffu + ((u >> 16) & 1u)) >> 16);
}

typedef __attribute__((address_space(3))) unsigned int lds_u32;
typedef __attribute__((address_space(1))) const unsigned int glb_u32;

DEV void gload16(const void* g, void* l) {
    __builtin_amdgcn_global_load_lds((glb_u32*)g, (lds_u32*)l, 16, 0, 0);
}

// ---------------- transpose We1: [R][C] f32 -> [C][R] (fp16*256 bits + f32 copy) ----------------
__global__ __launch_bounds__(256) void tr_we1(const float* __restrict__ src, int R, int C,
                                              u16* __restrict__ hT, float* __restrict__ fT) {
    __shared__ float t[32][33];
    int tx = threadIdx.x, ty = threadIdx.y;
    int c0 = blockIdx.x * 32, r0 = blockIdx.y * 32;
#pragma unroll
    for (int i = 0; i < 4; i++) {
        int r = r0 + ty + i * 8;
        t[ty + i * 8][tx] = src[(size_t)r * C + c0 + tx];
    }
    __syncthreads();
#pragma unroll
    for (int i = 0; i < 4; i++) {
        int c = c0 + ty + i * 8;
        float v = t[tx][ty + i * 8];
        size_t o = (size_t)c * R + r0 + tx;
        _Float16 hv = (_Float16)(v * 256.0f);
        hT[o] = __builtin_bit_cast(unsigned short, hv);
        fT[o] = v;
    }
}

// ---------------- transpose to bf16: [R][C] f32 -> [C][R] bf16 ----------------
__global__ __launch_bounds__(256) void tr_bf16(const float* __restrict__ src, int R, int C,
                                               u16* __restrict__ dst) {
    __shared__ float t[32][33];
    int tx = threadIdx.x, ty = threadIdx.y;
    int c0 = blockIdx.x * 32, r0 = blockIdx.y * 32;
#pragma unroll
    for (int i = 0; i < 4; i++) {
        int r = r0 + ty + i * 8;
        t[ty + i * 8][tx] = src[(size_t)r * C + c0 + tx];
    }
    __syncthreads();
#pragma unroll
    for (int i = 0; i < 4; i++) {
        int c = c0 + ty + i * 8;
        dst[(size_t)c * R + r0 + tx] = f2bf_rn(t[tx][ty + i * 8]);
    }
}

// ---------------- GEMM1: H = relu(X @ We1 + be1) via single-pass fp16 MFMA ----------------
// A = X f32 [4096][12288] staged to LDS as f32 (swizzled), cvt->fp16 on fragment read.
// B = W1hT fp16 (x256) [1024][12288]. Epilogue: acc/256 + bias, relu, f32 out.
// BM=64 BN=128 BK=64, 256 threads (4 waves 2x2).
__global__ __launch_bounds__(256) void gemm1_f16(const float* __restrict__ A,
                                                 const u16* __restrict__ BT,
                                                 const float* __restrict__ bias,
                                                 float* __restrict__ H) {
    constexpr int K = 12288, N = 1024;
    __shared__ __align__(16) float Af[64][64];   // 16KB, granule16 = 4 floats, swizzled
    __shared__ __align__(16) u16 Bs[128][64];    // 16KB, granule16 = 8 halfs, swizzled
    int tid = threadIdx.x, lane = tid & 63;
    int wid = tid >> 6, wr = wid >> 1, wc = wid & 1;
    int m0 = blockIdx.x * 64, n0 = blockIdx.y * 128;

    f32x4 acc[2][4] = {};
    for (int kt = 0; kt < K / 64; ++kt) {
        int k0 = kt * 64;
        // A: 64 rows x 16 granules (source-XOR swizzle, linear LDS dest)
#pragma unroll
        for (int i = 0; i < 4; i++) {
            int s = i * 256 + tid;
            int r = s >> 4, g = s & 15;
            int gs = (g & 8) | ((g ^ r) & 7);
            gload16(A + (size_t)(m0 + r) * K + k0 + gs * 4, &Af[r][g * 4]);
        }
        // B: 128 rows x 8 granules
#pragma unroll
        for (int i = 0; i < 4; i++) {
            int s = i * 256 + tid;
            int r = s >> 3, g = s & 7;
            int gs = (g ^ r) & 7;
            gload16(BT + (size_t)(n0 + r) * K + k0 + gs * 8, &Bs[r][g * 8]);
        }
        __syncthreads();
#pragma unroll
        for (int kk = 0; kk < 2; kk++) {
            int kb = kk * 32 + (lane >> 4) * 8;
            f16x8 af[2], bfr[4];
#pragma unroll
            for (int mi = 0; mi < 2; mi++) {
                int r = wr * 32 + mi * 16 + (lane & 15);
                int ra = r & 7;
                int g0 = kb >> 2;
                f32x4 lo4 = *(const f32x4*)&Af[r][(((g0 ^ ra) & 7) | (g0 & 8)) * 4];
                f32x4 hi4 = *(const f32x4*)&Af[r][((((g0 + 1) ^ ra) & 7) | ((g0 + 1) & 8)) * 4];
                f16x8 t;
#pragma unroll
                for (int j = 0; j < 4; j++) { t[j] = (_Float16)lo4[j]; t[j + 4] = (_Float16)hi4[j]; }
                af[mi] = t;
            }
#pragma unroll
            for (int ni = 0; ni < 4; ni++) {
                int r = wc * 64 + ni * 16 + (lane & 15);
                int g = ((kb >> 3) ^ r) & 7;
                bfr[ni] = __builtin_bit_cast(f16x8, *(const s16x8*)&Bs[r][g * 8]);
            }
#pragma unroll
            for (int mi = 0; mi < 2; mi++)
#pragma unroll
                for (int ni = 0; ni < 4; ni++)
                    acc[mi][ni] = __builtin_amdgcn_mfma_f32_16x16x32_f16(af[mi], bfr[ni], acc[mi][ni], 0, 0, 0);
        }
        __syncthreads();
    }
#pragma unroll
    for (int ni = 0; ni < 4; ni++) {
        int col = n0 + wc * 64 + ni * 16 + (lane & 15);
        float bv = bias[col];
#pragma unroll
        for (int mi = 0; mi < 2; mi++) {
            int rb = m0 + wr * 32 + mi * 16 + (lane >> 4) * 4;
#pragma unroll
            for (int j = 0; j < 4; j++) {
                float x = acc[mi][ni][j] * (1.0f / 256.0f) + bv;
                H[(size_t)(rb + j) * N + col] = x > 0.f ? x : 0.f;
            }
        }
    }
}

// ---------------- generic bf16 BT GEMM (swizzled), EPI: 1=relu->bf16, 2=sigmoid->f32 ----------------
template <int BM, int BN, int EPI>
__global__ __launch_bounds__(256) void gemm_bt(const u16* __restrict__ A,   // [M][K] bf16
                                               const u16* __restrict__ BT,  // [N][K] bf16
                                               const float* __restrict__ bias,
                                               void* __restrict__ Out, int M, int N, int K) {
    constexpr int WM = BM / 2, WN = BN / 2, MI = WM / 16, NI = WN / 16;
    __shared__ __align__(16) u16 As[BM][64];
    __shared__ __align__(16) u16 Bs[BN][64];
    int tid = threadIdx.x, lane = tid & 63, wid = tid >> 6;
    int wr = wid >> 1, wc = wid & 1;
    int m0 = blockIdx.x * BM, n0 = blockIdx.y * BN;
    f32x4 acc[MI][NI] = {};
    for (int kt = 0; kt < K / 64; ++kt) {
        int k0 = kt * 64;
#pragma unroll
        for (int i = 0; i < BM / 32; i++) {
            int s = i * 256 + tid;
            int r = s >> 3, g = s & 7;
            int gs = (g ^ r) & 7;
            gload16(A + (size_t)(m0 + r) * K + k0 + gs * 8, &As[r][g * 8]);
        }
#pragma unroll
        for (int i = 0; i < BN / 32; i++) {
            int s = i * 256 + tid;
            int r = s >> 3, g = s & 7;
            int gs = (g ^ r) & 7;
            gload16(BT + (size_t)(n0 + r) * K + k0 + gs * 8, &Bs[r][g * 8]);
        }
        __syncthreads();
#pragma unroll
        for (int kk = 0; kk < 2; kk++) {
            int kb = kk * 32 + (lane >> 4) * 8;
            bf16x8 af[MI], bfr[NI];
#pragma unroll
            for (int mi = 0; mi < MI; mi++) {
                int r = wr * WM + mi * 16 + (lane & 15);
                int g = ((kb >> 3) ^ r) & 7;
                af[mi] = __builtin_bit_cast(bf16x8, *(const s16x8*)&As[r][g * 8]);
            }
#pragma unroll
            for (int ni = 0; ni < NI; ni++) {
                int r = wc * WN + ni * 16 + (lane & 15);
                int g = ((kb >> 3) ^ r) & 7;
                bfr[ni] = __builtin_bit_cast(bf16x8, *(const s16x8*)&Bs[r][g * 8]);
            }
#pragma unroll
            for (int mi = 0; mi < MI; mi++)
#pragma unroll
                for (int ni = 0; ni < NI; ni++)
                    acc[mi][ni] = __builtin_amdgcn_mfma_f32_16x16x32_bf16(af[mi], bfr[ni], acc[mi][ni], 0, 0, 0);
        }
        __syncthreads();
    }
#pragma unroll
    for (int ni = 0; ni < NI; ni++) {
        int col = n0 + wc * WN + ni * 16 + (lane & 15);
        float bv = bias[col];
#pragma unroll
        for (int mi = 0; mi < MI; mi++) {
            int rb = m0 + wr * WM + mi * 16 + (lane >> 4) * 4;
#pragma unroll
            for (int j = 0; j < 4; j++) {
                float x = acc[mi][ni][j] + bv;
                if (EPI == 1) {
                    ((u16*)Out)[(size_t)(rb + j) * N + col] = f2bf_rn(x > 0.f ? x : 0.f);
                } else {
                    float s = 1.f / (1.f + __expf(-x));
                    ((float*)Out)[(size_t)(rb + j) * N + col] = s;
                }
            }
        }
    }
}

// ---------------- top-64 of 1024 per row: threshold via bit binary search ----------------
__global__ __launch_bounds__(256) void topk_kernel(const float* __restrict__ H,
                                                   u16* __restrict__ HM,
                                                   float* __restrict__ rowT,
                                                   unsigned* __restrict__ rowFlag) {
    int row = blockIdx.x * 4 + (threadIdx.x >> 6);
    int lane = threadIdx.x & 63;
    const float* hr = H + (size_t)row * 1024;
    float v[16];
#pragma unroll
    for (int i = 0; i < 4; i++) *(f32x4*)&v[i * 4] = *(const f32x4*)(hr + lane * 16 + i * 4);
    unsigned u[16];
#pragma unroll
    for (int i = 0; i < 16; i++) u[i] = __float_as_uint(v[i]);
    unsigned lo = 0;
    for (int b = 30; b >= 0; --b) {
        unsigned cand = lo | (1u << b);
        int c = 0;
#pragma unroll
        for (int i = 0; i < 16; i++) c += (u[i] >= cand);
#pragma unroll
        for (int off = 32; off; off >>= 1) c += __shfl_xor(c, off);
        if (c >= 64) lo = cand;
    }
    unsigned m2 = 0;
#pragma unroll
    for (int i = 0; i < 16; i++)
        if (u[i] < lo && u[i] > m2) m2 = u[i];
#pragma unroll
    for (int off = 32; off; off >>= 1) {
        unsigned o = __shfl_xor(m2, off);
        if (o > m2) m2 = o;
    }
    u16 o16[16];
#pragma unroll
    for (int i = 0; i < 16; i++) o16[i] = (u[i] >= lo) ? f2bf_rn(v[i]) : (u16)0;
    unsigned p[8];
#pragma unroll
    for (int i = 0; i < 8; i++) p[i] = (unsigned)o16[2 * i] | ((unsigned)o16[2 * i + 1] << 16);
    u16* dst = HM + (size_t)row * 1024 + lane * 16;
    *(uint4*)dst = make_uint4(p[0], p[1], p[2], p[3]);
    *(uint4*)(dst + 8) = make_uint4(p[4], p[5], p[6], p[7]);
    if (lane == 0) {
        rowT[row] = __uint_as_float(lo);
        float t = __uint_as_float(lo), s = __uint_as_float(m2);
        rowFlag[row] = (lo != 0u) && (t - s < SEL_BAND);
    }
}

// ---------------- fp64 fix-up of boundary-ambiguous selections ----------------
__global__ __launch_bounds__(64) void fixup_kernel(const float* __restrict__ H,
                                                   const float* __restrict__ X,
                                                   const float* __restrict__ W,  // [1024][12288] f32 (We1^T)
                                                   const float* __restrict__ be1,
                                                   const float* __restrict__ rowT,
                                                   const unsigned* __restrict__ rowFlag,
                                                   u16* __restrict__ HM) {
    int row = blockIdx.x;
    if (!rowFlag[row]) return;
    int lane = threadIdx.x;
    const float BAND = SEL_BAND;
    float Tf = rowT[row];
    const float* hr = H + (size_t)row * 1024;
    float v[16];
#pragma unroll
    for (int i = 0; i < 4; i++) *(f32x4*)&v[i * 4] = *(const f32x4*)(hr + lane * 16 + i * 4);
    __shared__ int bidx[64];
    __shared__ float bval[64];
    __shared__ double dval[64];
    int base = 0, csure = 0;
#pragma unroll
    for (int i = 0; i < 16; i++) {
        bool inb = fabsf(v[i] - Tf) <= BAND;
        csure += (v[i] > Tf + BAND);
        unsigned long long mk = __ballot(inb);
        if (inb) {
            int pos = base + __popcll(mk & ((1ull << lane) - 1ull));
            if (pos < 64) { bidx[pos] = lane * 16 + i; bval[pos] = v[i]; }
        }
        base += (int)__popcll(mk);
    }
#pragma unroll
    for (int off = 32; off; off >>= 1) csure += __shfl_xor(csure, off);
    int nb = base > 64 ? 64 : base;
    __syncthreads();
    if (nb < 2) return;
    int kband = 64 - csure;
    const float* xr = X + (size_t)row * 12288;
    for (int e = 0; e < nb; e++) {
        int j = bidx[e];
        const float* wp = W + (size_t)j * 12288;
        double s = 0.0;
        for (int k = lane; k < 12288; k += 64) s += (double)xr[k] * (double)wp[k];
#pragma unroll
        for (int off = 32; off; off >>= 1) s += __shfl_xor(s, off);
        if (lane == 0) dval[e] = s + (double)be1[j];
    }
    __syncthreads();
    if (lane < nb) {
        double me = dval[lane];
        int j = bidx[lane];
        int rank = 0;
        for (int f = 0; f < nb; f++) {
            double df = dval[f];
            rank += (df > me) || (df == me && bidx[f] < j);
        }
        bool keep = rank < kband;
        HM[(size_t)row * 1024 + j] = keep ? f2bf_rn(bval[lane]) : (u16)0;
    }
}

extern "C" void kernel_launch(void* const* d_in, const int* in_sizes, int n_in,
                              void* d_out, int out_size, void* d_ws, size_t ws_size,
                              hipStream_t stream) {
    const float* X   = (const float*)d_in[0];
    const float* We1 = (const float*)d_in[1];
    const float* be1 = (const float*)d_in[2];
    const float* Wd1 = (const float*)d_in[3];
    const float* bd1 = (const float*)d_in[4];
    const float* Wd2 = (const float*)d_in[5];
    const float* bd2 = (const float*)d_in[6];

    char* ws = (char*)d_ws;
    size_t off = 0;
    auto alloc = [&](size_t bytes) { void* p = ws + off; off += (bytes + 255) & ~(size_t)255; return p; };
    u16* W1hT   = (u16*)alloc(12288ull * 1024 * 2);     // fp16 bits, scaled x256, [1024][12288]
    float* We1Tf = (float*)alloc(12288ull * 1024 * 4);  // f32 [1024][12288] for fixup
    u16* Wd1T   = (u16*)alloc(1024ull * 1024 * 2);
    u16* Wd2T   = (u16*)alloc(1024ull * 12288 * 2);
    float* Hbuf = (float*)alloc(4096ull * 1024 * 4);
    u16* HM     = (u16*)alloc(4096ull * 1024 * 2);
    u16* Dbf    = (u16*)alloc(4096ull * 1024 * 2);
    float* rowT = (float*)alloc(4096 * 4);
    unsigned* rowFlag = (unsigned*)alloc(4096 * 4);

    dim3 tb(32, 8);
    tr_we1<<<dim3(1024 / 32, 12288 / 32), tb, 0, stream>>>(We1, 12288, 1024, W1hT, We1Tf);
    tr_bf16<<<dim3(1024 / 32, 1024 / 32), tb, 0, stream>>>(Wd1, 1024, 1024, Wd1T);
    tr_bf16<<<dim3(12288 / 32, 1024 / 32), tb, 0, stream>>>(Wd2, 1024, 12288, Wd2T);

    gemm1_f16<<<dim3(4096 / 64, 1024 / 128), 256, 0, stream>>>(X, W1hT, be1, Hbuf);
    topk_kernel<<<dim3(4096 / 4), 256, 0, stream>>>(Hbuf, HM, rowT, rowFlag);
    fixup_kernel<<<4096, 64, 0, stream>>>(Hbuf, X, We1Tf, be1, rowT, rowFlag, HM);
    gemm_bt<64, 128, 1><<<dim3(4096 / 64, 1024 / 128), 256, 0, stream>>>(HM, Wd1T, bd1, Dbf, 4096, 1024, 1024);
    gemm_bt<128, 128, 2><<<dim3(4096 / 128, 12288 / 128), 256, 0, stream>>>(Dbf, Wd2T, bd2, d_out, 4096, 12288, 1024);
}

// Round 3
// 643.968 us; speedup vs baseline: 1.8316x; 1.2722x over previous
//
#include <hip/hip_runtime.h>

typedef float f32x4 __attribute__((ext_vector_type(4)));
typedef __bf16 bf16x8 __attribute__((ext_vector_type(8)));
typedef _Float16 f16x8 __attribute__((ext_vector_type(8)));
typedef short s16x8 __attribute__((ext_vector_type(8)));
typedef unsigned short u16;

#define DEV static __device__ __forceinline__

#define SEL_BAND 2.0e-3f   // fp16-GEMM1 error band for exact re-ranking

DEV u16 f2bf_rn(float f) {
    unsigned u = __float_as_uint(f);
    return (u16)((u + 0x7fffu + ((u >> 16) & 1u)) >> 16);
}

typedef __attribute__((address_space(3))) unsigned int lds_u32;
typedef __attribute__((address_space(1))) const unsigned int glb_u32;

DEV void gload16(const void* g, void* l) {
    __builtin_amdgcn_global_load_lds((glb_u32*)g, (lds_u32*)l, 16, 0, 0);
}

// ---------------- transpose We1: [R][C] f32 -> [C][R] (fp16*256 bits + f32 copy) ----------------
__global__ __launch_bounds__(256) void tr_we1(const float* __restrict__ src, int R, int C,
                                              u16* __restrict__ hT, float* __restrict__ fT) {
    __shared__ float t[32][33];
    int tx = threadIdx.x, ty = threadIdx.y;
    int c0 = blockIdx.x * 32, r0 = blockIdx.y * 32;
#pragma unroll
    for (int i = 0; i < 4; i++) {
        int r = r0 + ty + i * 8;
        t[ty + i * 8][tx] = src[(size_t)r * C + c0 + tx];
    }
    __syncthreads();
#pragma unroll
    for (int i = 0; i < 4; i++) {
        int c = c0 + ty + i * 8;
        float v = t[tx][ty + i * 8];
        size_t o = (size_t)c * R + r0 + tx;
        _Float16 hv = (_Float16)(v * 256.0f);
        hT[o] = __builtin_bit_cast(unsigned short, hv);
        fT[o] = v;
    }
}

// ---------------- transpose to bf16: [R][C] f32 -> [C][R] bf16 ----------------
__global__ __launch_bounds__(256) void tr_bf16(const float* __restrict__ src, int R, int C,
                                               u16* __restrict__ dst) {
    __shared__ float t[32][33];
    int tx = threadIdx.x, ty = threadIdx.y;
    int c0 = blockIdx.x * 32, r0 = blockIdx.y * 32;
#pragma unroll
    for (int i = 0; i < 4; i++) {
        int r = r0 + ty + i * 8;
        t[ty + i * 8][tx] = src[(size_t)r * C + c0 + tx];
    }
    __syncthreads();
#pragma unroll
    for (int i = 0; i < 4; i++) {
        int c = c0 + ty + i * 8;
        dst[(size_t)c * R + r0 + tx] = f2bf_rn(t[tx][ty + i * 8]);
    }
}

// ---------------- GEMM1: H = relu(X @ We1 + be1) via single-pass fp16 MFMA ----------------
__global__ __launch_bounds__(256) void gemm1_f16(const float* __restrict__ A,
                                                 const u16* __restrict__ BT,
                                                 const float* __restrict__ bias,
                                                 float* __restrict__ H) {
    constexpr int K = 12288, N = 1024;
    __shared__ __align__(16) float Af[64][64];
    __shared__ __align__(16) u16 Bs[128][64];
    int tid = threadIdx.x, lane = tid & 63;
    int wid = tid >> 6, wr = wid >> 1, wc = wid & 1;
    int m0 = blockIdx.x * 64, n0 = blockIdx.y * 128;

    f32x4 acc[2][4] = {};
    for (int kt = 0; kt < K / 64; ++kt) {
        int k0 = kt * 64;
#pragma unroll
        for (int i = 0; i < 4; i++) {
            int s = i * 256 + tid;
            int r = s >> 4, g = s & 15;
            int gs = (g & 8) | ((g ^ r) & 7);
            gload16(A + (size_t)(m0 + r) * K + k0 + gs * 4, &Af[r][g * 4]);
        }
#pragma unroll
        for (int i = 0; i < 4; i++) {
            int s = i * 256 + tid;
            int r = s >> 3, g = s & 7;
            int gs = (g ^ r) & 7;
            gload16(BT + (size_t)(n0 + r) * K + k0 + gs * 8, &Bs[r][g * 8]);
        }
        __syncthreads();
#pragma unroll
        for (int kk = 0; kk < 2; kk++) {
            int kb = kk * 32 + (lane >> 4) * 8;
            f16x8 af[2], bfr[4];
#pragma unroll
            for (int mi = 0; mi < 2; mi++) {
                int r = wr * 32 + mi * 16 + (lane & 15);
                int ra = r & 7;
                int g0 = kb >> 2;
                f32x4 lo4 = *(const f32x4*)&Af[r][(((g0 ^ ra) & 7) | (g0 & 8)) * 4];
                f32x4 hi4 = *(const f32x4*)&Af[r][((((g0 + 1) ^ ra) & 7) | ((g0 + 1) & 8)) * 4];
                f16x8 t;
#pragma unroll
                for (int j = 0; j < 4; j++) { t[j] = (_Float16)lo4[j]; t[j + 4] = (_Float16)hi4[j]; }
                af[mi] = t;
            }
#pragma unroll
            for (int ni = 0; ni < 4; ni++) {
                int r = wc * 64 + ni * 16 + (lane & 15);
                int g = ((kb >> 3) ^ r) & 7;
                bfr[ni] = __builtin_bit_cast(f16x8, *(const s16x8*)&Bs[r][g * 8]);
            }
#pragma unroll
            for (int mi = 0; mi < 2; mi++)
#pragma unroll
                for (int ni = 0; ni < 4; ni++)
                    acc[mi][ni] = __builtin_amdgcn_mfma_f32_16x16x32_f16(af[mi], bfr[ni], acc[mi][ni], 0, 0, 0);
        }
        __syncthreads();
    }
#pragma unroll
    for (int ni = 0; ni < 4; ni++) {
        int col = n0 + wc * 64 + ni * 16 + (lane & 15);
        float bv = bias[col];
#pragma unroll
        for (int mi = 0; mi < 2; mi++) {
            int rb = m0 + wr * 32 + mi * 16 + (lane >> 4) * 4;
#pragma unroll
            for (int j = 0; j < 4; j++) {
                float x = acc[mi][ni][j] * (1.0f / 256.0f) + bv;
                H[(size_t)(rb + j) * N + col] = x > 0.f ? x : 0.f;
            }
        }
    }
}

// ---------------- generic bf16 BT GEMM (swizzled), EPI: 1=relu->bf16, 2=sigmoid->f32 ----------------
template <int BM, int BN, int EPI>
__global__ __launch_bounds__(256) void gemm_bt(const u16* __restrict__ A,   // [M][K] bf16
                                               const u16* __restrict__ BT,  // [N][K] bf16
                                               const float* __restrict__ bias,
                                               void* __restrict__ Out, int M, int N, int K) {
    constexpr int WM = BM / 2, WN = BN / 2, MI = WM / 16, NI = WN / 16;
    __shared__ __align__(16) u16 As[BM][64];
    __shared__ __align__(16) u16 Bs[BN][64];
    int tid = threadIdx.x, lane = tid & 63, wid = tid >> 6;
    int wr = wid >> 1, wc = wid & 1;
    int m0 = blockIdx.x * BM, n0 = blockIdx.y * BN;
    f32x4 acc[MI][NI] = {};
    for (int kt = 0; kt < K / 64; ++kt) {
        int k0 = kt * 64;
#pragma unroll
        for (int i = 0; i < BM / 32; i++) {
            int s = i * 256 + tid;
            int r = s >> 3, g = s & 7;
            int gs = (g ^ r) & 7;
            gload16(A + (size_t)(m0 + r) * K + k0 + gs * 8, &As[r][g * 8]);
        }
#pragma unroll
        for (int i = 0; i < BN / 32; i++) {
            int s = i * 256 + tid;
            int r = s >> 3, g = s & 7;
            int gs = (g ^ r) & 7;
            gload16(BT + (size_t)(n0 + r) * K + k0 + gs * 8, &Bs[r][g * 8]);
        }
        __syncthreads();
#pragma unroll
        for (int kk = 0; kk < 2; kk++) {
            int kb = kk * 32 + (lane >> 4) * 8;
            bf16x8 af[MI], bfr[NI];
#pragma unroll
            for (int mi = 0; mi < MI; mi++) {
                int r = wr * WM + mi * 16 + (lane & 15);
                int g = ((kb >> 3) ^ r) & 7;
                af[mi] = __builtin_bit_cast(bf16x8, *(const s16x8*)&As[r][g * 8]);
            }
#pragma unroll
            for (int ni = 0; ni < NI; ni++) {
                int r = wc * WN + ni * 16 + (lane & 15);
                int g = ((kb >> 3) ^ r) & 7;
                bfr[ni] = __builtin_bit_cast(bf16x8, *(const s16x8*)&Bs[r][g * 8]);
            }
#pragma unroll
            for (int mi = 0; mi < MI; mi++)
#pragma unroll
                for (int ni = 0; ni < NI; ni++)
                    acc[mi][ni] = __builtin_amdgcn_mfma_f32_16x16x32_bf16(af[mi], bfr[ni], acc[mi][ni], 0, 0, 0);
        }
        __syncthreads();
    }
#pragma unroll
    for (int ni = 0; ni < NI; ni++) {
        int col = n0 + wc * WN + ni * 16 + (lane & 15);
        float bv = bias[col];
#pragma unroll
        for (int mi = 0; mi < MI; mi++) {
            int rb = m0 + wr * WM + mi * 16 + (lane >> 4) * 4;
#pragma unroll
            for (int j = 0; j < 4; j++) {
                float x = acc[mi][ni][j] + bv;
                if (EPI == 1) {
                    ((u16*)Out)[(size_t)(rb + j) * N + col] = f2bf_rn(x > 0.f ? x : 0.f);
                } else {
                    float s = 1.f / (1.f + __expf(-x));
                    ((float*)Out)[(size_t)(rb + j) * N + col] = s;
                }
            }
        }
    }
}

// ---------------- top-64 of 1024 per row: threshold via bit binary search ----------------
__global__ __launch_bounds__(256) void topk_kernel(const float* __restrict__ H,
                                                   u16* __restrict__ HM,
                                                   float* __restrict__ rowT,
                                                   unsigned* __restrict__ rowFlag) {
    int row = blockIdx.x * 4 + (threadIdx.x >> 6);
    int lane = threadIdx.x & 63;
    const float* hr = H + (size_t)row * 1024;
    float v[16];
#pragma unroll
    for (int i = 0; i < 4; i++) *(f32x4*)&v[i * 4] = *(const f32x4*)(hr + lane * 16 + i * 4);
    unsigned u[16];
#pragma unroll
    for (int i = 0; i < 16; i++) u[i] = __float_as_uint(v[i]);
    unsigned lo = 0;
    for (int b = 30; b >= 0; --b) {
        unsigned cand = lo | (1u << b);
        int c = 0;
#pragma unroll
        for (int i = 0; i < 16; i++) c += (u[i] >= cand);
#pragma unroll
        for (int off = 32; off; off >>= 1) c += __shfl_xor(c, off);
        if (c >= 64) lo = cand;
    }
    unsigned m2 = 0;
#pragma unroll
    for (int i = 0; i < 16; i++)
        if (u[i] < lo && u[i] > m2) m2 = u[i];
#pragma unroll
    for (int off = 32; off; off >>= 1) {
        unsigned o = __shfl_xor(m2, off);
        if (o > m2) m2 = o;
    }
    u16 o16[16];
#pragma unroll
    for (int i = 0; i < 16; i++) o16[i] = (u[i] >= lo) ? f2bf_rn(v[i]) : (u16)0;
    unsigned p[8];
#pragma unroll
    for (int i = 0; i < 8; i++) p[i] = (unsigned)o16[2 * i] | ((unsigned)o16[2 * i + 1] << 16);
    u16* dst = HM + (size_t)row * 1024 + lane * 16;
    *(uint4*)dst = make_uint4(p[0], p[1], p[2], p[3]);
    *(uint4*)(dst + 8) = make_uint4(p[4], p[5], p[6], p[7]);
    if (lane == 0) {
        rowT[row] = __uint_as_float(lo);
        float t = __uint_as_float(lo), s = __uint_as_float(m2);
        rowFlag[row] = (lo != 0u) && (t - s < SEL_BAND);
    }
}

// ---------------- fp64 fix-up: 256 thr, wave-per-candidate, 4-chain dots ----------------
__global__ __launch_bounds__(256) void fixup_kernel(const float* __restrict__ H,
                                                    const float* __restrict__ X,
                                                    const float* __restrict__ W,  // [1024][12288] f32 (We1^T)
                                                    const float* __restrict__ be1,
                                                    const float* __restrict__ rowT,
                                                    const unsigned* __restrict__ rowFlag,
                                                    u16* __restrict__ HM) {
    int row = blockIdx.x;
    if (!rowFlag[row]) return;
    int tid = threadIdx.x, lane = tid & 63, wv = tid >> 6;
    float Tf = rowT[row];
    const float* hr = H + (size_t)row * 1024;
    f32x4 v = *(const f32x4*)(hr + tid * 4);
    __shared__ int bidx[64];
    __shared__ float bval[64];
    __shared__ double dval[64];
    __shared__ int cnt, csh;
    if (tid == 0) { cnt = 0; csh = 0; }
    __syncthreads();
    int myS = 0;
#pragma unroll
    for (int i = 0; i < 4; i++) {
        float x = v[i];
        if (fabsf(x - Tf) <= SEL_BAND) {
            int p = atomicAdd(&cnt, 1);
            if (p < 64) { bidx[p] = tid * 4 + i; bval[p] = x; }
        }
        myS += (x > Tf + SEL_BAND);
    }
#pragma unroll
    for (int off = 32; off; off >>= 1) myS += __shfl_xor(myS, off);
    if (lane == 0) atomicAdd(&csh, myS);
    __syncthreads();
    int nb = cnt < 64 ? cnt : 64;
    if (nb < 2) return;
    int kband = 64 - csh;
    const float* xr = X + (size_t)row * 12288;
    for (int e = wv; e < nb; e += 4) {
        const float* wp = W + (size_t)bidx[e] * 12288;
        double s0 = 0, s1 = 0, s2 = 0, s3 = 0;
        for (int k0 = 0; k0 < 12288; k0 += 256) {
            s0 += (double)xr[k0 + lane]       * (double)wp[k0 + lane];
            s1 += (double)xr[k0 + 64 + lane]  * (double)wp[k0 + 64 + lane];
            s2 += (double)xr[k0 + 128 + lane] * (double)wp[k0 + 128 + lane];
            s3 += (double)xr[k0 + 192 + lane] * (double)wp[k0 + 192 + lane];
        }
        double s = (s0 + s1) + (s2 + s3);
#pragma unroll
        for (int off = 32; off; off >>= 1) s += __shfl_xor(s, off);
        if (lane == 0) dval[e] = s + (double)be1[bidx[e]];
    }
    __syncthreads();
    if (tid < nb) {
        double me = dval[tid];
        int j = bidx[tid];
        int rank = 0;
        for (int f = 0; f < nb; f++) {
            double df = dval[f];
            rank += (df > me) || (df == me && bidx[f] < j);
        }
        HM[(size_t)row * 1024 + j] = (rank < kband) ? f2bf_rn(bval[tid]) : (u16)0;
    }
}

extern "C" void kernel_launch(void* const* d_in, const int* in_sizes, int n_in,
                              void* d_out, int out_size, void* d_ws, size_t ws_size,
                              hipStream_t stream) {
    const float* X   = (const float*)d_in[0];
    const float* We1 = (const float*)d_in[1];
    const float* be1 = (const float*)d_in[2];
    const float* Wd1 = (const float*)d_in[3];
    const float* bd1 = (const float*)d_in[4];
    const float* Wd2 = (const float*)d_in[5];
    const float* bd2 = (const float*)d_in[6];

    char* ws = (char*)d_ws;
    size_t off = 0;
    auto alloc = [&](size_t bytes) { void* p = ws + off; off += (bytes + 255) & ~(size_t)255; return p; };
    u16* W1hT   = (u16*)alloc(12288ull * 1024 * 2);     // fp16 bits, scaled x256, [1024][12288]
    float* We1Tf = (float*)alloc(12288ull * 1024 * 4);  // f32 [1024][12288] for fixup
    u16* Wd1T   = (u16*)alloc(1024ull * 1024 * 2);
    u16* Wd2T   = (u16*)alloc(1024ull * 12288 * 2);
    float* Hbuf = (float*)alloc(4096ull * 1024 * 4);
    u16* HM     = (u16*)alloc(4096ull * 1024 * 2);
    u16* Dbf    = (u16*)alloc(4096ull * 1024 * 2);
    float* rowT = (float*)alloc(4096 * 4);
    unsigned* rowFlag = (unsigned*)alloc(4096 * 4);

    dim3 tb(32, 8);
    tr_we1<<<dim3(1024 / 32, 12288 / 32), tb, 0, stream>>>(We1, 12288, 1024, W1hT, We1Tf);
    tr_bf16<<<dim3(1024 / 32, 1024 / 32), tb, 0, stream>>>(Wd1, 1024, 1024, Wd1T);
    tr_bf16<<<dim3(12288 / 32, 1024 / 32), tb, 0, stream>>>(Wd2, 1024, 12288, Wd2T);

    gemm1_f16<<<dim3(4096 / 64, 1024 / 128), 256, 0, stream>>>(X, W1hT, be1, Hbuf);
    topk_kernel<<<dim3(4096 / 4), 256, 0, stream>>>(Hbuf, HM, rowT, rowFlag);
    fixup_kernel<<<4096, 256, 0, stream>>>(Hbuf, X, We1Tf, be1, rowT, rowFlag, HM);
    gemm_bt<64, 128, 1><<<dim3(4096 / 64, 1024 / 128), 256, 0, stream>>>(HM, Wd1T, bd1, Dbf, 4096, 1024, 1024);
    gemm_bt<128, 128, 2><<<dim3(4096 / 128, 12288 / 128), 256, 0, stream>>>(Dbf, Wd2T, bd2, d_out, 4096, 12288, 1024);
}

// Round 4
// 605.337 us; speedup vs baseline: 1.9485x; 1.0638x over previous
//
#include <hip/hip_runtime.h>

typedef float f32x4 __attribute__((ext_vector_type(4)));
typedef __bf16 bf16x8 __attribute__((ext_vector_type(8)));
typedef _Float16 f16x8 __attribute__((ext_vector_type(8)));
typedef short s16x8 __attribute__((ext_vector_type(8)));
typedef unsigned short u16;

#define DEV static __device__ __forceinline__

#define SEL_BAND 2.0e-3f   // fp16-GEMM1 error band for exact re-ranking

DEV u16 f2bf_rn(float f) {
    unsigned u = __float_as_uint(f);
    return (u16)((u + 0x7fffu + ((u >> 16) & 1u)) >> 16);
}

typedef __attribute__((address_space(3))) unsigned int lds_u32;
typedef __attribute__((address_space(1))) const unsigned int glb_u32;

DEV void gload16(const void* g, void* l) {
    __builtin_amdgcn_global_load_lds((glb_u32*)g, (lds_u32*)l, 16, 0, 0);
}

// ---------------- transpose We1: [R][C] f32 -> [C][R] (fp16*256 bits + f32 copy) ----------------
__global__ __launch_bounds__(256) void tr_we1(const float* __restrict__ src, int R, int C,
                                              u16* __restrict__ hT, float* __restrict__ fT) {
    __shared__ float t[32][33];
    int tx = threadIdx.x, ty = threadIdx.y;
    int c0 = blockIdx.x * 32, r0 = blockIdx.y * 32;
#pragma unroll
    for (int i = 0; i < 4; i++) {
        int r = r0 + ty + i * 8;
        t[ty + i * 8][tx] = src[(size_t)r * C + c0 + tx];
    }
    __syncthreads();
#pragma unroll
    for (int i = 0; i < 4; i++) {
        int c = c0 + ty + i * 8;
        float v = t[tx][ty + i * 8];
        size_t o = (size_t)c * R + r0 + tx;
        _Float16 hv = (_Float16)(v * 256.0f);
        hT[o] = __builtin_bit_cast(unsigned short, hv);
        fT[o] = v;
    }
}

// ---------------- transpose to bf16: [R][C] f32 -> [C][R] bf16 ----------------
__global__ __launch_bounds__(256) void tr_bf16(const float* __restrict__ src, int R, int C,
                                               u16* __restrict__ dst) {
    __shared__ float t[32][33];
    int tx = threadIdx.x, ty = threadIdx.y;
    int c0 = blockIdx.x * 32, r0 = blockIdx.y * 32;
#pragma unroll
    for (int i = 0; i < 4; i++) {
        int r = r0 + ty + i * 8;
        t[ty + i * 8][tx] = src[(size_t)r * C + c0 + tx];
    }
    __syncthreads();
#pragma unroll
    for (int i = 0; i < 4; i++) {
        int c = c0 + ty + i * 8;
        dst[(size_t)c * R + r0 + tx] = f2bf_rn(t[tx][ty + i * 8]);
    }
}

// ---------------- unified double-buffered GEMM ----------------
// MODE 0: A f32 (cvt->f16 on read), f16 MFMA, epi = relu, f32 out, acc*(1/256)+bias (gemm1)
// MODE 1: A bf16, bf16 MFMA, epi = relu -> bf16 out (gemm2)
// MODE 2: A bf16, bf16 MFMA, epi = sigmoid -> f32 out (gemm3)
// 256 threads, 4 waves (2x2). Single __syncthreads per K-tile; prefetch next tile
// into the other LDS buffer before computing the current one (T3 minimum-2-phase).
// XCD-aware bijective swizzle, N-major chunking (each XCD: contiguous M-range, all N).
template <int BM, int BN, int MODE>
__global__ __launch_bounds__(256) void gemm_db(const void* __restrict__ Ap,
                                               const u16* __restrict__ BT,
                                               const float* __restrict__ bias,
                                               void* __restrict__ Out,
                                               int M, int N, int K) {
    constexpr int WM = BM / 2, WN = BN / 2, MI = WM / 16, NI = WN / 16;
    constexpr int ABYTES = BM * 64 * (MODE == 0 ? 4 : 2);
    constexpr int BBYTES = BN * 64 * 2;
    constexpr int STRIDE = ABYTES + BBYTES;
    __shared__ __align__(16) char lds[2 * STRIDE];

    int tid = threadIdx.x, lane = tid & 63, wid = tid >> 6;
    int wr = wid >> 1, wc = wid & 1;

    // XCD swizzle (nwg % 8 == 0 for all our grids)
    int lin = blockIdx.x + gridDim.x * blockIdx.y;
    int nwg = gridDim.x * gridDim.y;
    int q = nwg >> 3;
    int logical = (lin & 7) * q + (lin >> 3);
    int Ny = N / BN;
    int mb = logical / Ny, nb = logical - mb * Ny;
    int m0 = mb * BM, n0 = nb * BN;

    auto stage = [&](int kt, int c) {
        int k0 = kt * 64;
        char* bA = lds + c * STRIDE;
        char* bB = bA + ABYTES;
        if (MODE == 0) {
#pragma unroll
            for (int i = 0; i < BM / 16; i++) {
                int s = i * 256 + tid;
                int r = s >> 4, g = s & 15;
                int gs = (g & 8) | ((g ^ r) & 7);
                gload16((const float*)Ap + (size_t)(m0 + r) * K + k0 + gs * 4, bA + r * 256 + g * 16);
            }
        } else {
#pragma unroll
            for (int i = 0; i < BM / 32; i++) {
                int s = i * 256 + tid;
                int r = s >> 3, g = s & 7;
                int gs = (g ^ r) & 7;
                gload16((const u16*)Ap + (size_t)(m0 + r) * K + k0 + gs * 8, bA + r * 128 + g * 16);
            }
        }
#pragma unroll
        for (int i = 0; i < BN / 32; i++) {
            int s = i * 256 + tid;
            int r = s >> 3, g = s & 7;
            int gs = (g ^ r) & 7;
            gload16(BT + (size_t)(n0 + r) * K + k0 + gs * 8, bB + r * 128 + g * 16);
        }
    };

    f32x4 acc[MI][NI] = {};
    int NT = K / 64;
    stage(0, 0);
    __syncthreads();
    int cur = 0;
    for (int t = 0; t < NT; ++t) {
        if (t + 1 < NT) stage(t + 1, cur ^ 1);
        char* bA = lds + cur * STRIDE;
        char* bB = bA + ABYTES;
        const float* Afp = (const float*)bA;
        const u16* Aup = (const u16*)bA;
        const u16* Bup = (const u16*)bB;
#pragma unroll
        for (int kk = 0; kk < 2; kk++) {
            int kb = kk * 32 + (lane >> 4) * 8;
            if (MODE == 0) {
                f16x8 af[MI], bfr[NI];
#pragma unroll
                for (int mi = 0; mi < MI; mi++) {
                    int r = wr * WM + mi * 16 + (lane & 15);
                    int ra = r & 7;
                    int g0 = kb >> 2;
                    f32x4 lo4 = *(const f32x4*)&Afp[r * 64 + (((g0 ^ ra) & 7) | (g0 & 8)) * 4];
                    f32x4 hi4 = *(const f32x4*)&Afp[r * 64 + ((((g0 + 1) ^ ra) & 7) | ((g0 + 1) & 8)) * 4];
                    f16x8 tv;
#pragma unroll
                    for (int j = 0; j < 4; j++) { tv[j] = (_Float16)lo4[j]; tv[j + 4] = (_Float16)hi4[j]; }
                    af[mi] = tv;
                }
#pragma unroll
                for (int ni = 0; ni < NI; ni++) {
                    int r = wc * WN + ni * 16 + (lane & 15);
                    int g = ((kb >> 3) ^ r) & 7;
                    bfr[ni] = __builtin_bit_cast(f16x8, *(const s16x8*)&Bup[r * 64 + g * 8]);
                }
#pragma unroll
                for (int mi = 0; mi < MI; mi++)
#pragma unroll
                    for (int ni = 0; ni < NI; ni++)
                        acc[mi][ni] = __builtin_amdgcn_mfma_f32_16x16x32_f16(af[mi], bfr[ni], acc[mi][ni], 0, 0, 0);
            } else {
                bf16x8 af[MI], bfr[NI];
#pragma unroll
                for (int mi = 0; mi < MI; mi++) {
                    int r = wr * WM + mi * 16 + (lane & 15);
                    int g = ((kb >> 3) ^ r) & 7;
                    af[mi] = __builtin_bit_cast(bf16x8, *(const s16x8*)&Aup[r * 64 + g * 8]);
                }
#pragma unroll
                for (int ni = 0; ni < NI; ni++) {
                    int r = wc * WN + ni * 16 + (lane & 15);
                    int g = ((kb >> 3) ^ r) & 7;
                    bfr[ni] = __builtin_bit_cast(bf16x8, *(const s16x8*)&Bup[r * 64 + g * 8]);
                }
#pragma unroll
                for (int mi = 0; mi < MI; mi++)
#pragma unroll
                    for (int ni = 0; ni < NI; ni++)
                        acc[mi][ni] = __builtin_amdgcn_mfma_f32_16x16x32_bf16(af[mi], bfr[ni], acc[mi][ni], 0, 0, 0);
            }
        }
        __syncthreads();
        cur ^= 1;
    }
#pragma unroll
    for (int ni = 0; ni < NI; ni++) {
        int col = n0 + wc * WN + ni * 16 + (lane & 15);
        float bv = bias[col];
#pragma unroll
        for (int mi = 0; mi < MI; mi++) {
            int rb = m0 + wr * WM + mi * 16 + (lane >> 4) * 4;
#pragma unroll
            for (int j = 0; j < 4; j++) {
                float x = acc[mi][ni][j];
                if (MODE == 0) {
                    x = x * (1.0f / 256.0f) + bv;
                    ((float*)Out)[(size_t)(rb + j) * N + col] = x > 0.f ? x : 0.f;
                } else if (MODE == 1) {
                    x += bv;
                    ((u16*)Out)[(size_t)(rb + j) * N + col] = f2bf_rn(x > 0.f ? x : 0.f);
                } else {
                    x += bv;
                    ((float*)Out)[(size_t)(rb + j) * N + col] = 1.f / (1.f + __expf(-x));
                }
            }
        }
    }
}

// ---------------- top-64 of 1024 per row: threshold via bit binary search ----------------
__global__ __launch_bounds__(256) void topk_kernel(const float* __restrict__ H,
                                                   u16* __restrict__ HM,
                                                   float* __restrict__ rowT,
                                                   unsigned* __restrict__ rowFlag) {
    int row = blockIdx.x * 4 + (threadIdx.x >> 6);
    int lane = threadIdx.x & 63;
    const float* hr = H + (size_t)row * 1024;
    float v[16];
#pragma unroll
    for (int i = 0; i < 4; i++) *(f32x4*)&v[i * 4] = *(const f32x4*)(hr + lane * 16 + i * 4);
    unsigned u[16];
#pragma unroll
    for (int i = 0; i < 16; i++) u[i] = __float_as_uint(v[i]);
    unsigned lo = 0;
    for (int b = 30; b >= 0; --b) {
        unsigned cand = lo | (1u << b);
        int c = 0;
#pragma unroll
        for (int i = 0; i < 16; i++) c += (u[i] >= cand);
#pragma unroll
        for (int off = 32; off; off >>= 1) c += __shfl_xor(c, off);
        if (c >= 64) lo = cand;
    }
    unsigned m2 = 0;
#pragma unroll
    for (int i = 0; i < 16; i++)
        if (u[i] < lo && u[i] > m2) m2 = u[i];
#pragma unroll
    for (int off = 32; off; off >>= 1) {
        unsigned o = __shfl_xor(m2, off);
        if (o > m2) m2 = o;
    }
    u16 o16[16];
#pragma unroll
    for (int i = 0; i < 16; i++) o16[i] = (u[i] >= lo) ? f2bf_rn(v[i]) : (u16)0;
    unsigned p[8];
#pragma unroll
    for (int i = 0; i < 8; i++) p[i] = (unsigned)o16[2 * i] | ((unsigned)o16[2 * i + 1] << 16);
    u16* dst = HM + (size_t)row * 1024 + lane * 16;
    *(uint4*)dst = make_uint4(p[0], p[1], p[2], p[3]);
    *(uint4*)(dst + 8) = make_uint4(p[4], p[5], p[6], p[7]);
    if (lane == 0) {
        rowT[row] = __uint_as_float(lo);
        float t = __uint_as_float(lo), s = __uint_as_float(m2);
        rowFlag[row] = (lo != 0u) && (t - s < SEL_BAND);
    }
}

// ---------------- fp64 fix-up: 256 thr, wave-per-candidate, 4-chain dots ----------------
__global__ __launch_bounds__(256) void fixup_kernel(const float* __restrict__ H,
                                                    const float* __restrict__ X,
                                                    const float* __restrict__ W,  // [1024][12288] f32 (We1^T)
                                                    const float* __restrict__ be1,
                                                    const float* __restrict__ rowT,
                                                    const unsigned* __restrict__ rowFlag,
                                                    u16* __restrict__ HM) {
    int row = blockIdx.x;
    if (!rowFlag[row]) return;
    int tid = threadIdx.x, lane = tid & 63, wv = tid >> 6;
    float Tf = rowT[row];
    const float* hr = H + (size_t)row * 1024;
    f32x4 v = *(const f32x4*)(hr + tid * 4);
    __shared__ int bidx[64];
    __shared__ float bval[64];
    __shared__ double dval[64];
    __shared__ int cnt, csh;
    if (tid == 0) { cnt = 0; csh = 0; }
    __syncthreads();
    int myS = 0;
#pragma unroll
    for (int i = 0; i < 4; i++) {
        float x = v[i];
        if (fabsf(x - Tf) <= SEL_BAND) {
            int p = atomicAdd(&cnt, 1);
            if (p < 64) { bidx[p] = tid * 4 + i; bval[p] = x; }
        }
        myS += (x > Tf + SEL_BAND);
    }
#pragma unroll
    for (int off = 32; off; off >>= 1) myS += __shfl_xor(myS, off);
    if (lane == 0) atomicAdd(&csh, myS);
    __syncthreads();
    int nb = cnt < 64 ? cnt : 64;
    if (nb < 2) return;
    int kband = 64 - csh;
    const float* xr = X + (size_t)row * 12288;
    for (int e = wv; e < nb; e += 4) {
        const float* wp = W + (size_t)bidx[e] * 12288;
        double s0 = 0, s1 = 0, s2 = 0, s3 = 0;
        for (int k0 = 0; k0 < 12288; k0 += 256) {
            s0 += (double)xr[k0 + lane]       * (double)wp[k0 + lane];
            s1 += (double)xr[k0 + 64 + lane]  * (double)wp[k0 + 64 + lane];
            s2 += (double)xr[k0 + 128 + lane] * (double)wp[k0 + 128 + lane];
            s3 += (double)xr[k0 + 192 + lane] * (double)wp[k0 + 192 + lane];
        }
        double s = (s0 + s1) + (s2 + s3);
#pragma unroll
        for (int off = 32; off; off >>= 1) s += __shfl_xor(s, off);
        if (lane == 0) dval[e] = s + (double)be1[bidx[e]];
    }
    __syncthreads();
    if (tid < nb) {
        double me = dval[tid];
        int j = bidx[tid];
        int rank = 0;
        for (int f = 0; f < nb; f++) {
            double df = dval[f];
            rank += (df > me) || (df == me && bidx[f] < j);
        }
        HM[(size_t)row * 1024 + j] = (rank < kband) ? f2bf_rn(bval[tid]) : (u16)0;
    }
}

extern "C" void kernel_launch(void* const* d_in, const int* in_sizes, int n_in,
                              void* d_out, int out_size, void* d_ws, size_t ws_size,
                              hipStream_t stream) {
    const float* X   = (const float*)d_in[0];
    const float* We1 = (const float*)d_in[1];
    const float* be1 = (const float*)d_in[2];
    const float* Wd1 = (const float*)d_in[3];
    const float* bd1 = (const float*)d_in[4];
    const float* Wd2 = (const float*)d_in[5];
    const float* bd2 = (const float*)d_in[6];

    char* ws = (char*)d_ws;
    size_t off = 0;
    auto alloc = [&](size_t bytes) { void* p = ws + off; off += (bytes + 255) & ~(size_t)255; return p; };
    u16* W1hT   = (u16*)alloc(12288ull * 1024 * 2);     // fp16 bits, scaled x256, [1024][12288]
    float* We1Tf = (float*)alloc(12288ull * 1024 * 4);  // f32 [1024][12288] for fixup
    u16* Wd1T   = (u16*)alloc(1024ull * 1024 * 2);
    u16* Wd2T   = (u16*)alloc(1024ull * 12288 * 2);
    float* Hbuf = (float*)alloc(4096ull * 1024 * 4);
    u16* HM     = (u16*)alloc(4096ull * 1024 * 2);
    u16* Dbf    = (u16*)alloc(4096ull * 1024 * 2);
    float* rowT = (float*)alloc(4096 * 4);
    unsigned* rowFlag = (unsigned*)alloc(4096 * 4);

    dim3 tb(32, 8);
    tr_we1<<<dim3(1024 / 32, 12288 / 32), tb, 0, stream>>>(We1, 12288, 1024, W1hT, We1Tf);
    tr_bf16<<<dim3(1024 / 32, 1024 / 32), tb, 0, stream>>>(Wd1, 1024, 1024, Wd1T);
    tr_bf16<<<dim3(12288 / 32, 1024 / 32), tb, 0, stream>>>(Wd2, 1024, 12288, Wd2T);

    gemm_db<64, 128, 0><<<dim3(64, 8), 256, 0, stream>>>(X, W1hT, be1, Hbuf, 4096, 1024, 12288);
    topk_kernel<<<dim3(4096 / 4), 256, 0, stream>>>(Hbuf, HM, rowT, rowFlag);
    fixup_kernel<<<4096, 256, 0, stream>>>(Hbuf, X, We1Tf, be1, rowT, rowFlag, HM);
    gemm_db<64, 128, 1><<<dim3(64, 8), 256, 0, stream>>>(HM, Wd1T, bd1, Dbf, 4096, 1024, 1024);
    gemm_db<128, 128, 2><<<dim3(32, 96), 256, 0, stream>>>(Dbf, Wd2T, bd2, d_out, 4096, 12288, 1024);
}